// Round 6
// baseline (235.976 us; speedup 1.0000x reference)
//
#include <hip/hip_runtime.h>
#include <math.h>

#define HIDDEN 1024
#define SEQ 2048

typedef __attribute__((ext_vector_type(8))) short short8;
typedef __attribute__((ext_vector_type(4))) float f32x4;

__device__ __forceinline__ unsigned short f2bf(float x) {
  union { float f; unsigned u; } c; c.f = x;
  unsigned r = c.u + 0x7FFFu + ((c.u >> 16) & 1u);
  return (unsigned short)(r >> 16);
}
__device__ __forceinline__ float bf2f(unsigned short h) {
  union { unsigned u; float f; } c; c.u = ((unsigned)h) << 16;
  return c.f;
}

// raw v_exp_f32 (exp2) without libm edge-case wrapper
__device__ __forceinline__ float fexp2(float x) {
  float r; asm("v_exp_f32 %0, %1" : "=v"(r) : "v"(x)); return r;
}

// pack two f32 -> one reg of 2 bf16 (RNE), lo in low half
__device__ __forceinline__ unsigned cvt_pk_bf16(float lo, float hi) {
  unsigned r;
  asm("v_cvt_pk_bf16_f32 %0, %1, %2" : "=v"(r) : "v"(lo), "v"(hi));
  return r;
}

// async 16B global -> LDS (wave-uniform LDS base; HW scatters lane i to base+16i)
__device__ __forceinline__ void async_copy16(const void* g, void* l) {
  __builtin_amdgcn_global_load_lds(
      (const __attribute__((address_space(1))) unsigned int*)g,
      (__attribute__((address_space(3))) unsigned int*)l, 16, 0, 0);
}

// ---------------------------------------------------------------------------
// All fp32->bf16 converts in ONE dispatch.
// ---------------------------------------------------------------------------
__global__ __launch_bounds__(256) void cvt_all(
    const float* __restrict__ hs, const float* __restrict__ wq,
    const float* __restrict__ wk, const float* __restrict__ wv,
    const float* __restrict__ wo, const float* __restrict__ w1,
    const float* __restrict__ w2,
    unsigned short* __restrict__ hsb, unsigned short* __restrict__ wqb,
    unsigned short* __restrict__ wkb, unsigned short* __restrict__ wvb,
    unsigned short* __restrict__ wob, unsigned short* __restrict__ w1b,
    unsigned short* __restrict__ w2b)
{
  const int i = blockIdx.x * 256 + threadIdx.x;
  const float* src; unsigned short* dst; int off;
  if (i < 1048576)      { src = hs; dst = hsb; off = i; }
  else if (i < 1310720) { src = wq; dst = wqb; off = i - 1048576; }
  else if (i < 1376256) { src = wk; dst = wkb; off = i - 1310720; }
  else if (i < 1441792) { src = wv; dst = wvb; off = i - 1376256; }
  else if (i < 1703936) { src = wo; dst = wob; off = i - 1441792; }
  else if (i < 1966080) { src = w1; dst = w1b; off = i - 1703936; }
  else                  { src = w2; dst = w2b; off = i - 1966080; }
  float4 v = ((const float4*)src)[off];
  ushort4 o;
  o.x = f2bf(v.x); o.y = f2bf(v.y); o.z = f2bf(v.z); o.w = f2bf(v.w);
  ((ushort4*)dst)[off] = o;
}

// ---------------------------------------------------------------------------
// bf16 MFMA GEMM v16 "gemm128": 128x128 tile, 512 thr (8 waves 2x4, wave
// tile 64x32). R5 analysis: 64x64 structure is LDS-READ bound (1:1
// ds_read:MFMA, ~17us/gemm LDS floor). This tile: 12 reads : 16 MFMA
// (1.33:1) + staging bytes/FLOP halved -> LDS floor ~7us. Grid 256 =
// 1 block/CU (2 waves/SIMD); latency hidden by attn-proven counted
// vmcnt(4) double buffer (64 KB LDS). XCD-chunked swizzle.
// ---------------------------------------------------------------------------
template<bool RELU>
__global__ __launch_bounds__(512) void gemm128(
    const unsigned short* __restrict__ A, const unsigned short* __restrict__ W,
    const float* __restrict__ bias, unsigned short* __restrict__ C,
    int M, int N, int K)
{
  __shared__ unsigned short As[2][128 * 64];
  __shared__ unsigned short Bs[2][128 * 64];
  const int tid = threadIdx.x;
  const int lane = tid & 63, wave = tid >> 6;          // wave 0..7
  const int ln = lane & 15, quad = lane >> 4;
  const int wm = (wave >> 2) * 64, wn = (wave & 3) * 32;

  // XCD-chunked bijective swizzle (gridDim.x % 8 == 0)
  const int flat = blockIdx.x;
  const int swz = (flat & 7) * ((int)gridDim.x >> 3) + (flat >> 3);
  const int ntx = N >> 7;
  const int m0 = (swz / ntx) * 128, n0 = (swz % ntx) * 128;

  f32x4 acc[4][2];
#pragma unroll
  for (int i = 0; i < 4; ++i)
#pragma unroll
    for (int j = 0; j < 2; ++j) acc[i][j] = (f32x4){0.f, 0.f, 0.f, 0.f};

  auto stage = [&](int k0, int p) {
#pragma unroll
    for (int it = 0; it < 2; ++it) {
      const int c = (wave * 2 + it) * 64 + lane;       // 0..1023
      const int row = c >> 3, gc = (c & 7) ^ (row & 7);
      async_copy16(A + (size_t)(m0 + row) * K + k0 + gc * 8,
                   &As[p][(wave * 2 + it) * 512]);
    }
#pragma unroll
    for (int it = 0; it < 2; ++it) {
      const int c = (wave * 2 + it) * 64 + lane;
      const int row = c >> 3, gc = (c & 7) ^ (row & 7);
      async_copy16(W + (size_t)(n0 + row) * K + k0 + gc * 8,
                   &Bs[p][(wave * 2 + it) * 512]);
    }
  };  // 4 DMAs per wave

  stage(0, 0);
  const int NT = K >> 6;
  for (int t = 0; t < NT; ++t) {
    const int p = t & 1;
    if (t < NT - 1) {
      stage((t + 1) * 64, p ^ 1);                      // 4 new DMAs in flight
      asm volatile("s_waitcnt vmcnt(4)" ::: "memory"); // wait only step-t DMAs
    } else {
      asm volatile("s_waitcnt vmcnt(0)" ::: "memory");
    }
    __builtin_amdgcn_s_barrier();
    asm volatile("" ::: "memory");

    short8 af[4][2], bfr[2][2];
#pragma unroll
    for (int i = 0; i < 4; ++i) {
      const int row = wm + i * 16 + ln;
#pragma unroll
      for (int f = 0; f < 2; ++f) {
        const int ch = row * 8 + ((f * 4 + quad) ^ (row & 7));
        af[i][f] = *(const short8*)&As[p][ch * 8];
      }
    }
#pragma unroll
    for (int j = 0; j < 2; ++j) {
      const int row = wn + j * 16 + ln;
#pragma unroll
      for (int f = 0; f < 2; ++f) {
        const int ch = row * 8 + ((f * 4 + quad) ^ (row & 7));
        bfr[j][f] = *(const short8*)&Bs[p][ch * 8];
      }
    }
#pragma unroll
    for (int i = 0; i < 4; ++i)
#pragma unroll
      for (int j = 0; j < 2; ++j) {
        acc[i][j] = __builtin_amdgcn_mfma_f32_16x16x32_bf16(af[i][0], bfr[j][0], acc[i][j], 0, 0, 0);
        acc[i][j] = __builtin_amdgcn_mfma_f32_16x16x32_bf16(af[i][1], bfr[j][1], acc[i][j], 0, 0, 0);
      }

    asm volatile("" ::: "memory");
    __builtin_amdgcn_s_barrier();   // all reads done before next overwrite
    asm volatile("" ::: "memory");
  }

#pragma unroll
  for (int j = 0; j < 2; ++j) {
    const int n = n0 + wn + j * 16 + ln;
    const float bv = bias[n];
#pragma unroll
    for (int i = 0; i < 4; ++i) {
#pragma unroll
      for (int rr = 0; rr < 4; ++rr) {
        const int m = m0 + wm + i * 16 + quad * 4 + rr;
        float v = acc[i][j][rr] + bv;
        if (RELU) v = fmaxf(v, 0.f);
        C[(size_t)m * N + n] = f2bf(v);
      }
    }
  }
}

// ---------------------------------------------------------------------------
// Fused QKV GEMM: 64x128 tile, SINGLE-buffered (24 KB) -> 6 blocks/CU.
// (unchanged; control for gemm128 experiment)
// ---------------------------------------------------------------------------
__global__ __launch_bounds__(256) void gemm_qkv(
    const unsigned short* __restrict__ A,
    const unsigned short* __restrict__ Wq, const unsigned short* __restrict__ Wk,
    const unsigned short* __restrict__ Wv,
    const float* __restrict__ bq, const float* __restrict__ bk,
    const float* __restrict__ bv,
    unsigned short* __restrict__ Qo, unsigned short* __restrict__ Ko,
    unsigned short* __restrict__ Vt)
{
  __shared__ unsigned short As[64 * 64];
  __shared__ unsigned short Bs[128 * 64];

  const int flat = blockIdx.x;                 // 0..767
  const int swz = (flat & 7) * 96 + (flat >> 3);
  const int bx = swz % 12, by = swz / 12;

  int mode, nw0;
  const unsigned short* W;
  const float* bias;
  if (bx < 8)       { mode = 0; W = Wq; bias = bq; nw0 = bx * 128; }
  else if (bx < 10) { mode = 1; W = Wk; bias = bk; nw0 = (bx - 8) * 128; }
  else              { mode = 2; W = Wv; bias = bv; nw0 = (bx - 10) * 128; }

  const int tid = threadIdx.x;
  const int lane = tid & 63, wave = tid >> 6;
  const int ln = lane & 15, quad = lane >> 4;
  const int wm = (wave >> 1) * 32, wn = (wave & 1) * 64;
  const int m0 = by * 64;
  const int K = 1024;

  f32x4 acc[2][4];
#pragma unroll
  for (int i = 0; i < 2; ++i)
#pragma unroll
    for (int j = 0; j < 4; ++j) acc[i][j] = (f32x4){0.f, 0.f, 0.f, 0.f};

  for (int k0 = 0; k0 < K; k0 += 64) {
#pragma unroll
    for (int it = 0; it < 2; ++it) {
      const int c = (wave * 2 + it) * 64 + lane;
      const int row = c >> 3, gc = (c & 7) ^ (row & 7);
      async_copy16(A + (size_t)(m0 + row) * K + k0 + gc * 8,
                   &As[(wave * 2 + it) * 512]);
    }
#pragma unroll
    for (int it = 0; it < 4; ++it) {
      const int c = (wave * 4 + it) * 64 + lane;
      const int row = c >> 3, gc = (c & 7) ^ (row & 7);
      async_copy16(W + (size_t)(nw0 + row) * K + k0 + gc * 8,
                   &Bs[(wave * 4 + it) * 512]);
    }
    __syncthreads();

    short8 af[2][2], bfr[4][2];
#pragma unroll
    for (int i = 0; i < 2; ++i) {
      const int row = wm + i * 16 + ln;
#pragma unroll
      for (int f = 0; f < 2; ++f) {
        const int ch = row * 8 + ((f * 4 + quad) ^ (row & 7));
        af[i][f] = *(const short8*)&As[ch * 8];
      }
    }
#pragma unroll
    for (int j = 0; j < 4; ++j) {
      const int row = wn + j * 16 + ln;
#pragma unroll
      for (int f = 0; f < 2; ++f) {
        const int ch = row * 8 + ((f * 4 + quad) ^ (row & 7));
        bfr[j][f] = *(const short8*)&Bs[ch * 8];
      }
    }
#pragma unroll
    for (int i = 0; i < 2; ++i)
#pragma unroll
      for (int j = 0; j < 4; ++j) {
        acc[i][j] = __builtin_amdgcn_mfma_f32_16x16x32_bf16(af[i][0], bfr[j][0], acc[i][j], 0, 0, 0);
        acc[i][j] = __builtin_amdgcn_mfma_f32_16x16x32_bf16(af[i][1], bfr[j][1], acc[i][j], 0, 0, 0);
      }
    __syncthreads();
  }

#pragma unroll
  for (int j = 0; j < 4; ++j) {
    const int nl = nw0 + wn + j * 16 + ln;
    const float bvv = bias[nl];
#pragma unroll
    for (int i = 0; i < 2; ++i) {
#pragma unroll
      for (int rr = 0; rr < 4; ++rr) {
        const int m = m0 + wm + i * 16 + quad * 4 + rr;
        const float v = acc[i][j][rr] + bvv;
        if (mode == 0) {
          Qo[(size_t)m * 1024 + nl] = f2bf(v);
        } else if (mode == 1) {
          Ko[(size_t)m * 256 + nl] = f2bf(v);
        } else {
          const int b = m >> 11, s = m & 2047;
          Vt[((size_t)b * 256 + nl) * SEQ + s] = f2bf(v);
        }
      }
    }
  }
}

// ---------------------------------------------------------------------------
// MFMA flash attention v16: split-KV, 8 waves x qg=2 per 512-thr block.
//   R5 post-mortem: occupancy fix confirmed (41.5us @ 8 waves/CU); stalls
//   still ~3.5x LDS floor. This keeps grid 512 but packs 2 blocks/CU x
//   8 waves = 16 waves/CU (4/SIMD, 2x TLP) at VGPR<=128 (qg=2 state).
//   +30% LDS traffic vs qg=4, traded for 2x latency hiding.
//   sigma key-perm in-register P (conflicts=0), dbuf K/V 32 KB,
//   counted vmcnt(2), XCD chunk = one (b,g).
// ---------------------------------------------------------------------------
__global__ __launch_bounds__(512, 4) void attn_mfma(
    const unsigned short* __restrict__ Q, const unsigned short* __restrict__ Kb,
    const unsigned short* __restrict__ Vt,
    unsigned short* __restrict__ N0, unsigned short* __restrict__ N1,
    float* __restrict__ LS)
{
  __shared__ unsigned short Ks[2][64 * 64];
  __shared__ unsigned short Vs[2][64 * 64];

  // XCD-chunked bijective swizzle over 512 blocks (chunk of 64 = one (b,g))
  const int hwb = blockIdx.x;
  const int swz = (hwb & 7) * 64 + (hwb >> 3);
  const int qblk = swz & 7, half = (swz >> 3) & 1, h = (swz >> 4) & 15, b = swz >> 8;
  const int g = h >> 2;

  unsigned short* __restrict__ numO = half ? N1 : N0;
  float* __restrict__ lsO = LS + half * 65536;

  const int tid = threadIdx.x, lane = tid & 63, wave = tid >> 6;  // wave 0..7
  const int ln = lane & 15, quad = lane >> 4, q8 = quad * 8;
  const int s0 = qblk * 256;
  const float qscale = 0.125f * 1.44269504f;  // softmax scale * log2(e)

  // swizzle constants
  const int ln7 = ln & 7;
  const int x0 = (quad ^ ln7) * 8;        // K/V chunk offset for cols q8
  const int x1 = ((4 + quad) ^ ln7) * 8;  // for cols 32+q8

  // all-ones bf16 B-frag for MFMA row-sums
  short8 ones;
#pragma unroll
  for (int e = 0; e < 8; ++e) ones[e] = (short)0x3F80;

  // ---- Q B-frags straight from global, pre-scaled (2 q-groups per wave)
  short8 qf[2][2];
#pragma unroll
  for (int qg = 0; qg < 2; ++qg) {
    const unsigned short* qsrc =
        Q + ((size_t)(b * SEQ + s0 + wave * 32 + qg * 16 + ln)) * 1024 + h * 64 + q8;
    qf[qg][0] = *(const short8*)qsrc;
    qf[qg][1] = *(const short8*)(qsrc + 32);
#pragma unroll
    for (int e = 0; e < 8; ++e) {
      qf[qg][0][e] = (short)f2bf(bf2f((unsigned short)qf[qg][0][e]) * qscale);
      qf[qg][1][e] = (short)f2bf(bf2f((unsigned short)qf[qg][1][e]) * qscale);
    }
  }

  // staging: wave w stages chunk-group w (rows w*8..w*8+7); 2 DMAs/wave
  const int srow = lane >> 3;
  const int sgcc = (lane & 7) ^ srow;

  auto stage = [&](int t0, int p) {
    const int row = wave * 8 + srow;
    // sigma: key bit perm {r5,r3,r2,r4,r1,r0} -> QK out slots == PV A-frag
    const int skey = (row & 32) | ((row & 8) << 1) | ((row & 4) << 1) |
                     ((row & 16) >> 2) | (row & 3);
    async_copy16(Kb + (size_t)(b * SEQ + t0 + skey) * 256 + g * 64 + sgcc * 8,
                 &Ks[p][wave * 512]);
    async_copy16(Vt + (size_t)(b * 256 + g * 64 + row) * SEQ + t0 + sgcc * 8,
                 &Vs[p][wave * 512]);
  };

  f32x4 of[2][4];
  f32x4 ls[2];
#pragma unroll
  for (int qg = 0; qg < 2; ++qg) {
    ls[qg] = (f32x4){0.f, 0.f, 0.f, 0.f};
#pragma unroll
    for (int jd = 0; jd < 4; ++jd) of[qg][jd] = (f32x4){0.f, 0.f, 0.f, 0.f};
  }

  const int tbase = half * 16;          // this half's first KV tile
  stage(tbase * 64, 0);                 // prologue prefetch (2 DMAs/wave)

  for (int tt = 0; tt < 16; ++tt) {
    const int p = tt & 1;
    if (tt < 15) {
      stage((tbase + tt + 1) * 64, p ^ 1);             // 2 new DMAs in flight
      asm volatile("s_waitcnt vmcnt(2)" ::: "memory"); // wait only tile-t DMAs
    } else {
      asm volatile("s_waitcnt vmcnt(0)" ::: "memory");
    }
    __builtin_amdgcn_s_barrier();                      // tile t fully in LDS
    asm volatile("" ::: "memory");

    // ---- K^T·Q: kf frags shared by both q-groups
    f32x4 sc[2][4];
#pragma unroll
    for (int jn = 0; jn < 4; ++jn) {
      const int krow = (jn * 16 + ln) * 64;
      const short8 kf0 = *(const short8*)&Ks[p][krow + x0];
      const short8 kf1 = *(const short8*)&Ks[p][krow + x1];
#pragma unroll
      for (int qg = 0; qg < 2; ++qg) {
        f32x4 z = (f32x4){0.f, 0.f, 0.f, 0.f};
        z = __builtin_amdgcn_mfma_f32_16x16x32_bf16(kf0, qf[qg][0], z, 0, 0, 0);
        z = __builtin_amdgcn_mfma_f32_16x16x32_bf16(kf1, qf[qg][1], z, 0, 0, 0);
        sc[qg][jn] = z;
      }
    }

    // ---- exp2 + in-register bf16 P build (lane-local thanks to sigma)
    short8 pf[2][2];
#pragma unroll
    for (int qg = 0; qg < 2; ++qg) {
#pragma unroll
      for (int jn = 0; jn < 4; ++jn)
#pragma unroll
        for (int r = 0; r < 4; ++r) sc[qg][jn][r] = fexp2(sc[qg][jn][r]);
#pragma unroll
      for (int F = 0; F < 2; ++F) {
        union { unsigned u[4]; short8 s; } pk;
        pk.u[0] = cvt_pk_bf16(sc[qg][2 * F][0], sc[qg][2 * F][1]);
        pk.u[1] = cvt_pk_bf16(sc[qg][2 * F][2], sc[qg][2 * F][3]);
        pk.u[2] = cvt_pk_bf16(sc[qg][2 * F + 1][0], sc[qg][2 * F + 1][1]);
        pk.u[3] = cvt_pk_bf16(sc[qg][2 * F + 1][2], sc[qg][2 * F + 1][3]);
        pf[qg][F] = pk.s;
      }
      ls[qg] = __builtin_amdgcn_mfma_f32_16x16x32_bf16(pf[qg][0], ones, ls[qg], 0, 0, 0);
      ls[qg] = __builtin_amdgcn_mfma_f32_16x16x32_bf16(pf[qg][1], ones, ls[qg], 0, 0, 0);
    }

    // ---- PV: vf frags shared by both q-groups (natural key order)
#pragma unroll
    for (int jd = 0; jd < 4; ++jd) {
      const int vrow = (jd * 16 + ln) * 64;
      const short8 vf0 = *(const short8*)&Vs[p][vrow + x0];
      const short8 vf1 = *(const short8*)&Vs[p][vrow + x1];
#pragma unroll
      for (int qg = 0; qg < 2; ++qg) {
        of[qg][jd] = __builtin_amdgcn_mfma_f32_16x16x32_bf16(pf[qg][0], vf0, of[qg][jd], 0, 0, 0);
        of[qg][jd] = __builtin_amdgcn_mfma_f32_16x16x32_bf16(pf[qg][1], vf1, of[qg][jd], 0, 0, 0);
      }
    }

    asm volatile("" ::: "memory");
    __builtin_amdgcn_s_barrier();   // all buf-p reads done before t+1 overwrites
    asm volatile("" ::: "memory");
  }

  // ---- UNNORMALIZED packed numerator store + row-sum store
#pragma unroll
  for (int qg = 0; qg < 2; ++qg) {
    const int sbase = s0 + wave * 32 + qg * 16 + quad * 4;
    if (ln == 0) {  // lanes 0,16,32,48: ls for rows quad*4+r
#pragma unroll
      for (int r = 0; r < 4; ++r)
        lsO[(b * 16 + h) * 2048 + sbase + r] = ls[qg][r];
    }
#pragma unroll
    for (int jd = 0; jd < 4; ++jd) {
      const int d = jd * 16 + ln;
      ushort4 ov;
      ov.x = f2bf(of[qg][jd][0]);
      ov.y = f2bf(of[qg][jd][1]);
      ov.z = f2bf(of[qg][jd][2]);
      ov.w = f2bf(of[qg][jd][3]);
      *(ushort4*)&numO[((size_t)b * 1024 + h * 64 + d) * SEQ + sbase] = ov;
    }
  }
}

// ---------------------------------------------------------------------------
// Split-KV reduce: att = (num0 + att{=num1}) / (ls0 + ls1). In-place safe.
// ---------------------------------------------------------------------------
__global__ __launch_bounds__(256) void attn_reduce(
    const unsigned short* __restrict__ N0, unsigned short* att,
    const float* __restrict__ LS)
{
  const int i = (blockIdx.x * 256 + threadIdx.x) * 4;  // flat into [b][1024][2048]
  const int row = i >> 11, s = i & 2047;
  const int h = (row >> 6) & 15, b = row >> 10;
  const int lsi = (b * 16 + h) * 2048 + s;
  const float4 l0 = *(const float4*)&LS[lsi];
  const float4 l1 = *(const float4*)&LS[65536 + lsi];
  const ushort4 a = *(const ushort4*)&N0[i];
  const ushort4 c = *(const ushort4*)&att[i];
  ushort4 o;
  o.x = f2bf((bf2f(a.x) + bf2f(c.x)) / (l0.x + l1.x));
  o.y = f2bf((bf2f(a.y) + bf2f(c.y)) / (l0.y + l1.y));
  o.z = f2bf((bf2f(a.z) + bf2f(c.z)) / (l0.z + l1.z));
  o.w = f2bf((bf2f(a.w) + bf2f(c.w)) / (l0.w + l1.w));
  *(ushort4*)&att[i] = o;
}

// ---------------------------------------------------------------------------
// Residual + LayerNorm. One block per row (1024 cols), 256 thr x 4.
// ---------------------------------------------------------------------------
__device__ __forceinline__ void ln_core(float x[4], const float* gam, const float* bet,
                                        int tid, float out[4]) {
  float s1 = x[0] + x[1] + x[2] + x[3];
  float s2 = x[0] * x[0] + x[1] * x[1] + x[2] * x[2] + x[3] * x[3];
#pragma unroll
  for (int off = 1; off < 64; off <<= 1) {
    s1 += __shfl_xor(s1, off);
    s2 += __shfl_xor(s2, off);
  }
  __shared__ float r1[4], r2[4];
  const int wave = tid >> 6;
  if ((tid & 63) == 0) { r1[wave] = s1; r2[wave] = s2; }
  __syncthreads();
  s1 = r1[0] + r1[1] + r1[2] + r1[3];
  s2 = r2[0] + r2[1] + r2[2] + r2[3];
  const float mu  = s1 * (1.0f / HIDDEN);
  const float var = s2 * (1.0f / HIDDEN) - mu * mu;
  const float inv = rsqrtf(var + 1e-5f);
  float4 gv = *(const float4*)&gam[tid * 4];
  float4 bv = *(const float4*)&bet[tid * 4];
  out[0] = (x[0] - mu) * inv * gv.x + bv.x;
  out[1] = (x[1] - mu) * inv * gv.y + bv.y;
  out[2] = (x[2] - mu) * inv * gv.z + bv.z;
  out[3] = (x[3] - mu) * inv * gv.w + bv.w;
}

__global__ __launch_bounds__(256) void resid_ln1(
    const float* __restrict__ X, const unsigned short* __restrict__ Y,
    const float* __restrict__ gam, const float* __restrict__ bet,
    unsigned short* __restrict__ outb)
{
  const int row = blockIdx.x, tid = threadIdx.x;
  const size_t base = (size_t)row * HIDDEN + tid * 4;
  float4 a = *(const float4*)&X[base];
  ushort4 yv = *(const ushort4*)&Y[base];
  float x[4] = {a.x + bf2f(yv.x), a.y + bf2f(yv.y), a.z + bf2f(yv.z), a.w + bf2f(yv.w)};
  float o[4];
  ln_core(x, gam, bet, tid, o);
  ushort4 ov;
  ov.x = f2bf(o[0]); ov.y = f2bf(o[1]); ov.z = f2bf(o[2]); ov.w = f2bf(o[3]);
  *(ushort4*)&outb[base] = ov;
}

__global__ __launch_bounds__(256) void resid_ln2(
    const unsigned short* __restrict__ X, const unsigned short* __restrict__ Y,
    const float* __restrict__ gam, const float* __restrict__ bet,
    float* __restrict__ out)
{
  const int row = blockIdx.x, tid = threadIdx.x;
  const size_t base = (size_t)row * HIDDEN + tid * 4;
  ushort4 xv = *(const ushort4*)&X[base];
  ushort4 yv = *(const ushort4*)&Y[base];
  float x[4] = {bf2f(xv.x) + bf2f(yv.x), bf2f(xv.y) + bf2f(yv.y),
                bf2f(xv.z) + bf2f(yv.z), bf2f(xv.w) + bf2f(yv.w)};
  float o[4];
  ln_core(x, gam, bet, tid, o);
  float4 ov; ov.x = o[0]; ov.y = o[1]; ov.z = o[2]; ov.w = o[3];
  *(float4*)&out[base] = ov;
}

// ---------------------------------------------------------------------------
extern "C" void kernel_launch(void* const* d_in, const int* in_sizes, int n_in,
                              void* d_out, int out_size, void* d_ws, size_t ws_size,
                              hipStream_t stream)
{
  (void)in_sizes; (void)n_in; (void)out_size; (void)ws_size;
  const float* hs  = (const float*)d_in[0];
  const float* wq  = (const float*)d_in[1];
  const float* bq  = (const float*)d_in[2];
  const float* wk  = (const float*)d_in[3];
  const float* bk  = (const float*)d_in[4];
  const float* wv  = (const float*)d_in[5];
  const float* bvp = (const float*)d_in[6];
  const float* wo  = (const float*)d_in[7];
  const float* bo  = (const float*)d_in[8];
  const float* lng = (const float*)d_in[9];
  const float* lnb = (const float*)d_in[10];
  const float* w1  = (const float*)d_in[11];
  const float* b1  = (const float*)d_in[12];
  const float* w2  = (const float*)d_in[13];
  const float* b2  = (const float*)d_in[14];
  const float* flg = (const float*)d_in[15];
  const float* flb = (const float*)d_in[16];
  float* out = (float*)d_out;

  unsigned short* w = (unsigned short*)d_ws;
  unsigned short* wqb = w;                    // 1048576  (dead after gemm_qkv -> ls buf)
  unsigned short* wkb = w + 1048576;          //  262144
  unsigned short* wvb = w + 1310720;          //  262144
  unsigned short* wob = w + 1572864;          // 1048576
  unsigned short* w1b = w + 2621440;          // 1048576
  unsigned short* w2b = w + 3670016;          // 1048576
  unsigned short* hsb = w + 4718592;          // 4194304  (dead after gemm_qkv -> num0; reused: f1b)
  unsigned short* qb  = w + 8912896;          // 4194304  (reused: yb, f2b)
  unsigned short* kb  = w + 13107200;         // 1048576
  unsigned short* vt  = w + 14155776;         // 1048576
  unsigned short* att = w + 15204352;         // 4194304  (num1 -> reduced in place; reused: obb)
  unsigned short* f1b = hsb;
  unsigned short* yb  = qb;
  unsigned short* obb = att;
  unsigned short* f2b = qb;
  float* lsbuf = (float*)wqb;                 // 2 x 65536 f32 = 512 KB

  dim3 blk(256);
  cvt_all<<<dim3(8704), blk, 0, stream>>>(hs, wq, wk, wv, wo, w1, w2,
                                          hsb, wqb, wkb, wvb, wob, w1b, w2b);

  gemm_qkv<<<dim3(768), blk, 0, stream>>>(hsb, wqb, wkb, wvb, bq, bk, bvp,
                                          qb, kb, vt);
  attn_mfma<<<dim3(512), dim3(512), 0, stream>>>(qb, kb, vt, hsb, att, lsbuf);
  attn_reduce<<<dim3(4096), blk, 0, stream>>>(hsb, att, lsbuf);
  gemm128<false><<<dim3(256), dim3(512), 0, stream>>>(att, wob, bo, yb, 4096, 1024, 1024);
  resid_ln1<<<dim3(4096), blk, 0, stream>>>(hs, yb, lng, lnb, obb);
  gemm128<true><<<dim3(256), dim3(512), 0, stream>>>(obb, w1b, b1, f1b, 4096, 1024, 1024);
  gemm128<false><<<dim3(256), dim3(512), 0, stream>>>(f1b, w2b, b2, f2b, 4096, 1024, 1024);
  resid_ln2<<<dim3(4096), blk, 0, stream>>>(obb, f2b, flg, flb, out);
}

// Round 7
// 234.922 us; speedup vs baseline: 1.0045x; 1.0045x over previous
//
#include <hip/hip_runtime.h>
#include <math.h>

#define HIDDEN 1024
#define SEQ 2048

typedef __attribute__((ext_vector_type(8))) short short8;
typedef __attribute__((ext_vector_type(4))) float f32x4;

__device__ __forceinline__ unsigned short f2bf(float x) {
  union { float f; unsigned u; } c; c.f = x;
  unsigned r = c.u + 0x7FFFu + ((c.u >> 16) & 1u);
  return (unsigned short)(r >> 16);
}
__device__ __forceinline__ float bf2f(unsigned short h) {
  union { unsigned u; float f; } c; c.u = ((unsigned)h) << 16;
  return c.f;
}

// raw v_exp_f32 (exp2) without libm edge-case wrapper
__device__ __forceinline__ float fexp2(float x) {
  float r; asm("v_exp_f32 %0, %1" : "=v"(r) : "v"(x)); return r;
}

// pack two f32 -> one reg of 2 bf16 (RNE), lo in low half
__device__ __forceinline__ unsigned cvt_pk_bf16(float lo, float hi) {
  unsigned r;
  asm("v_cvt_pk_bf16_f32 %0, %1, %2" : "=v"(r) : "v"(lo), "v"(hi));
  return r;
}

// async 16B global -> LDS (wave-uniform LDS base; HW scatters lane i to base+16i)
__device__ __forceinline__ void async_copy16(const void* g, void* l) {
  __builtin_amdgcn_global_load_lds(
      (const __attribute__((address_space(1))) unsigned int*)g,
      (__attribute__((address_space(3))) unsigned int*)l, 16, 0, 0);
}

// ---------------------------------------------------------------------------
// All fp32->bf16 converts in ONE dispatch.
// ---------------------------------------------------------------------------
__global__ __launch_bounds__(256) void cvt_all(
    const float* __restrict__ hs, const float* __restrict__ wq,
    const float* __restrict__ wk, const float* __restrict__ wv,
    const float* __restrict__ wo, const float* __restrict__ w1,
    const float* __restrict__ w2,
    unsigned short* __restrict__ hsb, unsigned short* __restrict__ wqb,
    unsigned short* __restrict__ wkb, unsigned short* __restrict__ wvb,
    unsigned short* __restrict__ wob, unsigned short* __restrict__ w1b,
    unsigned short* __restrict__ w2b)
{
  const int i = blockIdx.x * 256 + threadIdx.x;
  const float* src; unsigned short* dst; int off;
  if (i < 1048576)      { src = hs; dst = hsb; off = i; }
  else if (i < 1310720) { src = wq; dst = wqb; off = i - 1048576; }
  else if (i < 1376256) { src = wk; dst = wkb; off = i - 1310720; }
  else if (i < 1441792) { src = wv; dst = wvb; off = i - 1376256; }
  else if (i < 1703936) { src = wo; dst = wob; off = i - 1441792; }
  else if (i < 1966080) { src = w1; dst = w1b; off = i - 1703936; }
  else                  { src = w2; dst = w2b; off = i - 1966080; }
  float4 v = ((const float4*)src)[off];
  ushort4 o;
  o.x = f2bf(v.x); o.y = f2bf(v.y); o.z = f2bf(v.z); o.w = f2bf(v.w);
  ((ushort4*)dst)[off] = o;
}

// ---------------------------------------------------------------------------
// bf16 MFMA GEMM v17 "gemm_wn": the gemm_qkv structure (measured 322 TF vs
// 64x64's 208 TF in THIS pipeline) applied to the 3 main GEMMs. 64x128
// tile, SINGLE-buffered 24 KB LDS -> 6 blocks/CU (24 waves/CU), 256 thr,
// wave-tile 32x64 (12 ds_read : 16 MFMA = 0.75). R2's gemm_wide test of
// this tile was confounded (added dbuf -> 2 blocks/CU); this keeps the
// occupancy. XCD-chunked bijective swizzle, grid (N/128)*(M/64) % 8 == 0.
// ---------------------------------------------------------------------------
template<bool RELU>
__global__ __launch_bounds__(256) void gemm_wn(
    const unsigned short* __restrict__ A, const unsigned short* __restrict__ W,
    const float* __restrict__ bias, unsigned short* __restrict__ C,
    int M, int N, int K)
{
  __shared__ unsigned short As[64 * 64];
  __shared__ unsigned short Bs[128 * 64];

  const int flat = blockIdx.x;
  const int swz = (flat & 7) * ((int)gridDim.x >> 3) + (flat >> 3);
  const int ntx = N >> 7;
  const int m0 = (swz / ntx) * 64, n0 = (swz % ntx) * 128;

  const int tid = threadIdx.x;
  const int lane = tid & 63, wave = tid >> 6;
  const int ln = lane & 15, quad = lane >> 4;
  const int wm = (wave >> 1) * 32, wn = (wave & 1) * 64;

  f32x4 acc[2][4];
#pragma unroll
  for (int i = 0; i < 2; ++i)
#pragma unroll
    for (int j = 0; j < 4; ++j) acc[i][j] = (f32x4){0.f, 0.f, 0.f, 0.f};

  for (int k0 = 0; k0 < K; k0 += 64) {
#pragma unroll
    for (int it = 0; it < 2; ++it) {
      const int c = (wave * 2 + it) * 64 + lane;
      const int row = c >> 3, gc = (c & 7) ^ (row & 7);
      async_copy16(A + (size_t)(m0 + row) * K + k0 + gc * 8,
                   &As[(wave * 2 + it) * 512]);
    }
#pragma unroll
    for (int it = 0; it < 4; ++it) {
      const int c = (wave * 4 + it) * 64 + lane;
      const int row = c >> 3, gc = (c & 7) ^ (row & 7);
      async_copy16(W + (size_t)(n0 + row) * K + k0 + gc * 8,
                   &Bs[(wave * 4 + it) * 512]);
    }
    __syncthreads();

    short8 af[2][2], bfr[4][2];
#pragma unroll
    for (int i = 0; i < 2; ++i) {
      const int row = wm + i * 16 + ln;
#pragma unroll
      for (int f = 0; f < 2; ++f) {
        const int ch = row * 8 + ((f * 4 + quad) ^ (row & 7));
        af[i][f] = *(const short8*)&As[ch * 8];
      }
    }
#pragma unroll
    for (int j = 0; j < 4; ++j) {
      const int row = wn + j * 16 + ln;
#pragma unroll
      for (int f = 0; f < 2; ++f) {
        const int ch = row * 8 + ((f * 4 + quad) ^ (row & 7));
        bfr[j][f] = *(const short8*)&Bs[ch * 8];
      }
    }
#pragma unroll
    for (int i = 0; i < 2; ++i)
#pragma unroll
      for (int j = 0; j < 4; ++j) {
        acc[i][j] = __builtin_amdgcn_mfma_f32_16x16x32_bf16(af[i][0], bfr[j][0], acc[i][j], 0, 0, 0);
        acc[i][j] = __builtin_amdgcn_mfma_f32_16x16x32_bf16(af[i][1], bfr[j][1], acc[i][j], 0, 0, 0);
      }
    __syncthreads();
  }

#pragma unroll
  for (int j = 0; j < 4; ++j) {
    const int n = n0 + wn + j * 16 + ln;
    const float bv = bias[n];
#pragma unroll
    for (int i = 0; i < 2; ++i) {
#pragma unroll
      for (int rr = 0; rr < 4; ++rr) {
        const int m = m0 + wm + i * 16 + quad * 4 + rr;
        float v = acc[i][j][rr] + bv;
        if (RELU) v = fmaxf(v, 0.f);
        C[(size_t)m * N + n] = f2bf(v);
      }
    }
  }
}

// ---------------------------------------------------------------------------
// Fused QKV GEMM: 64x128 tile, SINGLE-buffered (24 KB) -> 6 blocks/CU.
// (unchanged)
// ---------------------------------------------------------------------------
__global__ __launch_bounds__(256) void gemm_qkv(
    const unsigned short* __restrict__ A,
    const unsigned short* __restrict__ Wq, const unsigned short* __restrict__ Wk,
    const unsigned short* __restrict__ Wv,
    const float* __restrict__ bq, const float* __restrict__ bk,
    const float* __restrict__ bv,
    unsigned short* __restrict__ Qo, unsigned short* __restrict__ Ko,
    unsigned short* __restrict__ Vt)
{
  __shared__ unsigned short As[64 * 64];
  __shared__ unsigned short Bs[128 * 64];

  const int flat = blockIdx.x;                 // 0..767
  const int swz = (flat & 7) * 96 + (flat >> 3);
  const int bx = swz % 12, by = swz / 12;

  int mode, nw0;
  const unsigned short* W;
  const float* bias;
  if (bx < 8)       { mode = 0; W = Wq; bias = bq; nw0 = bx * 128; }
  else if (bx < 10) { mode = 1; W = Wk; bias = bk; nw0 = (bx - 8) * 128; }
  else              { mode = 2; W = Wv; bias = bv; nw0 = (bx - 10) * 128; }

  const int tid = threadIdx.x;
  const int lane = tid & 63, wave = tid >> 6;
  const int ln = lane & 15, quad = lane >> 4;
  const int wm = (wave >> 1) * 32, wn = (wave & 1) * 64;
  const int m0 = by * 64;
  const int K = 1024;

  f32x4 acc[2][4];
#pragma unroll
  for (int i = 0; i < 2; ++i)
#pragma unroll
    for (int j = 0; j < 4; ++j) acc[i][j] = (f32x4){0.f, 0.f, 0.f, 0.f};

  for (int k0 = 0; k0 < K; k0 += 64) {
#pragma unroll
    for (int it = 0; it < 2; ++it) {
      const int c = (wave * 2 + it) * 64 + lane;
      const int row = c >> 3, gc = (c & 7) ^ (row & 7);
      async_copy16(A + (size_t)(m0 + row) * K + k0 + gc * 8,
                   &As[(wave * 2 + it) * 512]);
    }
#pragma unroll
    for (int it = 0; it < 4; ++it) {
      const int c = (wave * 4 + it) * 64 + lane;
      const int row = c >> 3, gc = (c & 7) ^ (row & 7);
      async_copy16(W + (size_t)(nw0 + row) * K + k0 + gc * 8,
                   &Bs[(wave * 4 + it) * 512]);
    }
    __syncthreads();

    short8 af[2][2], bfr[4][2];
#pragma unroll
    for (int i = 0; i < 2; ++i) {
      const int row = wm + i * 16 + ln;
#pragma unroll
      for (int f = 0; f < 2; ++f) {
        const int ch = row * 8 + ((f * 4 + quad) ^ (row & 7));
        af[i][f] = *(const short8*)&As[ch * 8];
      }
    }
#pragma unroll
    for (int j = 0; j < 4; ++j) {
      const int row = wn + j * 16 + ln;
#pragma unroll
      for (int f = 0; f < 2; ++f) {
        const int ch = row * 8 + ((f * 4 + quad) ^ (row & 7));
        bfr[j][f] = *(const short8*)&Bs[ch * 8];
      }
    }
#pragma unroll
    for (int i = 0; i < 2; ++i)
#pragma unroll
      for (int j = 0; j < 4; ++j) {
        acc[i][j] = __builtin_amdgcn_mfma_f32_16x16x32_bf16(af[i][0], bfr[j][0], acc[i][j], 0, 0, 0);
        acc[i][j] = __builtin_amdgcn_mfma_f32_16x16x32_bf16(af[i][1], bfr[j][1], acc[i][j], 0, 0, 0);
      }
    __syncthreads();
  }

#pragma unroll
  for (int j = 0; j < 4; ++j) {
    const int nl = nw0 + wn + j * 16 + ln;
    const float bvv = bias[nl];
#pragma unroll
    for (int i = 0; i < 2; ++i) {
#pragma unroll
      for (int rr = 0; rr < 4; ++rr) {
        const int m = m0 + wm + i * 16 + quad * 4 + rr;
        const float v = acc[i][j][rr] + bvv;
        if (mode == 0) {
          Qo[(size_t)m * 1024 + nl] = f2bf(v);
        } else if (mode == 1) {
          Ko[(size_t)m * 256 + nl] = f2bf(v);
        } else {
          const int b = m >> 11, s = m & 2047;
          Vt[((size_t)b * 256 + nl) * SEQ + s] = f2bf(v);
        }
      }
    }
  }
}

// ---------------------------------------------------------------------------
// MFMA flash attention v16: split-KV, 8 waves x qg=2 per 512-thr block,
// 2 blocks/CU x 8 waves = 16 waves/CU. sigma key-perm in-register P
// (conflicts=0), dbuf K/V 32 KB, counted vmcnt(2), XCD chunk = one (b,g).
// (unchanged from R6)
// ---------------------------------------------------------------------------
__global__ __launch_bounds__(512, 4) void attn_mfma(
    const unsigned short* __restrict__ Q, const unsigned short* __restrict__ Kb,
    const unsigned short* __restrict__ Vt,
    unsigned short* __restrict__ N0, unsigned short* __restrict__ N1,
    float* __restrict__ LS)
{
  __shared__ unsigned short Ks[2][64 * 64];
  __shared__ unsigned short Vs[2][64 * 64];

  // XCD-chunked bijective swizzle over 512 blocks (chunk of 64 = one (b,g))
  const int hwb = blockIdx.x;
  const int swz = (hwb & 7) * 64 + (hwb >> 3);
  const int qblk = swz & 7, half = (swz >> 3) & 1, h = (swz >> 4) & 15, b = swz >> 8;
  const int g = h >> 2;

  unsigned short* __restrict__ numO = half ? N1 : N0;
  float* __restrict__ lsO = LS + half * 65536;

  const int tid = threadIdx.x, lane = tid & 63, wave = tid >> 6;  // wave 0..7
  const int ln = lane & 15, quad = lane >> 4, q8 = quad * 8;
  const int s0 = qblk * 256;
  const float qscale = 0.125f * 1.44269504f;  // softmax scale * log2(e)

  // swizzle constants
  const int ln7 = ln & 7;
  const int x0 = (quad ^ ln7) * 8;        // K/V chunk offset for cols q8
  const int x1 = ((4 + quad) ^ ln7) * 8;  // for cols 32+q8

  // all-ones bf16 B-frag for MFMA row-sums
  short8 ones;
#pragma unroll
  for (int e = 0; e < 8; ++e) ones[e] = (short)0x3F80;

  // ---- Q B-frags straight from global, pre-scaled (2 q-groups per wave)
  short8 qf[2][2];
#pragma unroll
  for (int qg = 0; qg < 2; ++qg) {
    const unsigned short* qsrc =
        Q + ((size_t)(b * SEQ + s0 + wave * 32 + qg * 16 + ln)) * 1024 + h * 64 + q8;
    qf[qg][0] = *(const short8*)qsrc;
    qf[qg][1] = *(const short8*)(qsrc + 32);
#pragma unroll
    for (int e = 0; e < 8; ++e) {
      qf[qg][0][e] = (short)f2bf(bf2f((unsigned short)qf[qg][0][e]) * qscale);
      qf[qg][1][e] = (short)f2bf(bf2f((unsigned short)qf[qg][1][e]) * qscale);
    }
  }

  // staging: wave w stages chunk-group w (rows w*8..w*8+7); 2 DMAs/wave
  const int srow = lane >> 3;
  const int sgcc = (lane & 7) ^ srow;

  auto stage = [&](int t0, int p) {
    const int row = wave * 8 + srow;
    // sigma: key bit perm {r5,r3,r2,r4,r1,r0} -> QK out slots == PV A-frag
    const int skey = (row & 32) | ((row & 8) << 1) | ((row & 4) << 1) |
                     ((row & 16) >> 2) | (row & 3);
    async_copy16(Kb + (size_t)(b * SEQ + t0 + skey) * 256 + g * 64 + sgcc * 8,
                 &Ks[p][wave * 512]);
    async_copy16(Vt + (size_t)(b * 256 + g * 64 + row) * SEQ + t0 + sgcc * 8,
                 &Vs[p][wave * 512]);
  };

  f32x4 of[2][4];
  f32x4 ls[2];
#pragma unroll
  for (int qg = 0; qg < 2; ++qg) {
    ls[qg] = (f32x4){0.f, 0.f, 0.f, 0.f};
#pragma unroll
    for (int jd = 0; jd < 4; ++jd) of[qg][jd] = (f32x4){0.f, 0.f, 0.f, 0.f};
  }

  const int tbase = half * 16;          // this half's first KV tile
  stage(tbase * 64, 0);                 // prologue prefetch (2 DMAs/wave)

  for (int tt = 0; tt < 16; ++tt) {
    const int p = tt & 1;
    if (tt < 15) {
      stage((tbase + tt + 1) * 64, p ^ 1);             // 2 new DMAs in flight
      asm volatile("s_waitcnt vmcnt(2)" ::: "memory"); // wait only tile-t DMAs
    } else {
      asm volatile("s_waitcnt vmcnt(0)" ::: "memory");
    }
    __builtin_amdgcn_s_barrier();                      // tile t fully in LDS
    asm volatile("" ::: "memory");

    // ---- K^T·Q: kf frags shared by both q-groups
    f32x4 sc[2][4];
#pragma unroll
    for (int jn = 0; jn < 4; ++jn) {
      const int krow = (jn * 16 + ln) * 64;
      const short8 kf0 = *(const short8*)&Ks[p][krow + x0];
      const short8 kf1 = *(const short8*)&Ks[p][krow + x1];
#pragma unroll
      for (int qg = 0; qg < 2; ++qg) {
        f32x4 z = (f32x4){0.f, 0.f, 0.f, 0.f};
        z = __builtin_amdgcn_mfma_f32_16x16x32_bf16(kf0, qf[qg][0], z, 0, 0, 0);
        z = __builtin_amdgcn_mfma_f32_16x16x32_bf16(kf1, qf[qg][1], z, 0, 0, 0);
        sc[qg][jn] = z;
      }
    }

    // ---- exp2 + in-register bf16 P build (lane-local thanks to sigma)
    short8 pf[2][2];
#pragma unroll
    for (int qg = 0; qg < 2; ++qg) {
#pragma unroll
      for (int jn = 0; jn < 4; ++jn)
#pragma unroll
        for (int r = 0; r < 4; ++r) sc[qg][jn][r] = fexp2(sc[qg][jn][r]);
#pragma unroll
      for (int F = 0; F < 2; ++F) {
        union { unsigned u[4]; short8 s; } pk;
        pk.u[0] = cvt_pk_bf16(sc[qg][2 * F][0], sc[qg][2 * F][1]);
        pk.u[1] = cvt_pk_bf16(sc[qg][2 * F][2], sc[qg][2 * F][3]);
        pk.u[2] = cvt_pk_bf16(sc[qg][2 * F + 1][0], sc[qg][2 * F + 1][1]);
        pk.u[3] = cvt_pk_bf16(sc[qg][2 * F + 1][2], sc[qg][2 * F + 1][3]);
        pf[qg][F] = pk.s;
      }
      ls[qg] = __builtin_amdgcn_mfma_f32_16x16x32_bf16(pf[qg][0], ones, ls[qg], 0, 0, 0);
      ls[qg] = __builtin_amdgcn_mfma_f32_16x16x32_bf16(pf[qg][1], ones, ls[qg], 0, 0, 0);
    }

    // ---- PV: vf frags shared by both q-groups (natural key order)
#pragma unroll
    for (int jd = 0; jd < 4; ++jd) {
      const int vrow = (jd * 16 + ln) * 64;
      const short8 vf0 = *(const short8*)&Vs[p][vrow + x0];
      const short8 vf1 = *(const short8*)&Vs[p][vrow + x1];
#pragma unroll
      for (int qg = 0; qg < 2; ++qg) {
        of[qg][jd] = __builtin_amdgcn_mfma_f32_16x16x32_bf16(pf[qg][0], vf0, of[qg][jd], 0, 0, 0);
        of[qg][jd] = __builtin_amdgcn_mfma_f32_16x16x32_bf16(pf[qg][1], vf1, of[qg][jd], 0, 0, 0);
      }
    }

    asm volatile("" ::: "memory");
    __builtin_amdgcn_s_barrier();   // all buf-p reads done before t+1 overwrites
    asm volatile("" ::: "memory");
  }

  // ---- UNNORMALIZED packed numerator store + row-sum store
#pragma unroll
  for (int qg = 0; qg < 2; ++qg) {
    const int sbase = s0 + wave * 32 + qg * 16 + quad * 4;
    if (ln == 0) {  // lanes 0,16,32,48: ls for rows quad*4+r
#pragma unroll
      for (int r = 0; r < 4; ++r)
        lsO[(b * 16 + h) * 2048 + sbase + r] = ls[qg][r];
    }
#pragma unroll
    for (int jd = 0; jd < 4; ++jd) {
      const int d = jd * 16 + ln;
      ushort4 ov;
      ov.x = f2bf(of[qg][jd][0]);
      ov.y = f2bf(of[qg][jd][1]);
      ov.z = f2bf(of[qg][jd][2]);
      ov.w = f2bf(of[qg][jd][3]);
      *(ushort4*)&numO[((size_t)b * 1024 + h * 64 + d) * SEQ + sbase] = ov;
    }
  }
}

// ---------------------------------------------------------------------------
// Split-KV reduce: att = (num0 + att{=num1}) / (ls0 + ls1). In-place safe.
// ---------------------------------------------------------------------------
__global__ __launch_bounds__(256) void attn_reduce(
    const unsigned short* __restrict__ N0, unsigned short* att,
    const float* __restrict__ LS)
{
  const int i = (blockIdx.x * 256 + threadIdx.x) * 4;  // flat into [b][1024][2048]
  const int row = i >> 11, s = i & 2047;
  const int h = (row >> 6) & 15, b = row >> 10;
  const int lsi = (b * 16 + h) * 2048 + s;
  const float4 l0 = *(const float4*)&LS[lsi];
  const float4 l1 = *(const float4*)&LS[65536 + lsi];
  const ushort4 a = *(const ushort4*)&N0[i];
  const ushort4 c = *(const ushort4*)&att[i];
  ushort4 o;
  o.x = f2bf((bf2f(a.x) + bf2f(c.x)) / (l0.x + l1.x));
  o.y = f2bf((bf2f(a.y) + bf2f(c.y)) / (l0.y + l1.y));
  o.z = f2bf((bf2f(a.z) + bf2f(c.z)) / (l0.z + l1.z));
  o.w = f2bf((bf2f(a.w) + bf2f(c.w)) / (l0.w + l1.w));
  *(ushort4*)&att[i] = o;
}

// ---------------------------------------------------------------------------
// Residual + LayerNorm. One block per row (1024 cols), 256 thr x 4.
// ---------------------------------------------------------------------------
__device__ __forceinline__ void ln_core(float x[4], const float* gam, const float* bet,
                                        int tid, float out[4]) {
  float s1 = x[0] + x[1] + x[2] + x[3];
  float s2 = x[0] * x[0] + x[1] * x[1] + x[2] * x[2] + x[3] * x[3];
#pragma unroll
  for (int off = 1; off < 64; off <<= 1) {
    s1 += __shfl_xor(s1, off);
    s2 += __shfl_xor(s2, off);
  }
  __shared__ float r1[4], r2[4];
  const int wave = tid >> 6;
  if ((tid & 63) == 0) { r1[wave] = s1; r2[wave] = s2; }
  __syncthreads();
  s1 = r1[0] + r1[1] + r1[2] + r1[3];
  s2 = r2[0] + r2[1] + r2[2] + r2[3];
  const float mu  = s1 * (1.0f / HIDDEN);
  const float var = s2 * (1.0f / HIDDEN) - mu * mu;
  const float inv = rsqrtf(var + 1e-5f);
  float4 gv = *(const float4*)&gam[tid * 4];
  float4 bv = *(const float4*)&bet[tid * 4];
  out[0] = (x[0] - mu) * inv * gv.x + bv.x;
  out[1] = (x[1] - mu) * inv * gv.y + bv.y;
  out[2] = (x[2] - mu) * inv * gv.z + bv.z;
  out[3] = (x[3] - mu) * inv * gv.w + bv.w;
}

__global__ __launch_bounds__(256) void resid_ln1(
    const float* __restrict__ X, const unsigned short* __restrict__ Y,
    const float* __restrict__ gam, const float* __restrict__ bet,
    unsigned short* __restrict__ outb)
{
  const int row = blockIdx.x, tid = threadIdx.x;
  const size_t base = (size_t)row * HIDDEN + tid * 4;
  float4 a = *(const float4*)&X[base];
  ushort4 yv = *(const ushort4*)&Y[base];
  float x[4] = {a.x + bf2f(yv.x), a.y + bf2f(yv.y), a.z + bf2f(yv.z), a.w + bf2f(yv.w)};
  float o[4];
  ln_core(x, gam, bet, tid, o);
  ushort4 ov;
  ov.x = f2bf(o[0]); ov.y = f2bf(o[1]); ov.z = f2bf(o[2]); ov.w = f2bf(o[3]);
  *(ushort4*)&outb[base] = ov;
}

__global__ __launch_bounds__(256) void resid_ln2(
    const unsigned short* __restrict__ X, const unsigned short* __restrict__ Y,
    const float* __restrict__ gam, const float* __restrict__ bet,
    float* __restrict__ out)
{
  const int row = blockIdx.x, tid = threadIdx.x;
  const size_t base = (size_t)row * HIDDEN + tid * 4;
  ushort4 xv = *(const ushort4*)&X[base];
  ushort4 yv = *(const ushort4*)&Y[base];
  float x[4] = {bf2f(xv.x) + bf2f(yv.x), bf2f(xv.y) + bf2f(yv.y),
                bf2f(xv.z) + bf2f(yv.z), bf2f(xv.w) + bf2f(yv.w)};
  float o[4];
  ln_core(x, gam, bet, tid, o);
  float4 ov; ov.x = o[0]; ov.y = o[1]; ov.z = o[2]; ov.w = o[3];
  *(float4*)&out[base] = ov;
}

// ---------------------------------------------------------------------------
extern "C" void kernel_launch(void* const* d_in, const int* in_sizes, int n_in,
                              void* d_out, int out_size, void* d_ws, size_t ws_size,
                              hipStream_t stream)
{
  (void)in_sizes; (void)n_in; (void)out_size; (void)ws_size;
  const float* hs  = (const float*)d_in[0];
  const float* wq  = (const float*)d_in[1];
  const float* bq  = (const float*)d_in[2];
  const float* wk  = (const float*)d_in[3];
  const float* bk  = (const float*)d_in[4];
  const float* wv  = (const float*)d_in[5];
  const float* bvp = (const float*)d_in[6];
  const float* wo  = (const float*)d_in[7];
  const float* bo  = (const float*)d_in[8];
  const float* lng = (const float*)d_in[9];
  const float* lnb = (const float*)d_in[10];
  const float* w1  = (const float*)d_in[11];
  const float* b1  = (const float*)d_in[12];
  const float* w2  = (const float*)d_in[13];
  const float* b2  = (const float*)d_in[14];
  const float* flg = (const float*)d_in[15];
  const float* flb = (const float*)d_in[16];
  float* out = (float*)d_out;

  unsigned short* w = (unsigned short*)d_ws;
  unsigned short* wqb = w;                    // 1048576  (dead after gemm_qkv -> ls buf)
  unsigned short* wkb = w + 1048576;          //  262144
  unsigned short* wvb = w + 1310720;          //  262144
  unsigned short* wob = w + 1572864;          // 1048576
  unsigned short* w1b = w + 2621440;          // 1048576
  unsigned short* w2b = w + 3670016;          // 1048576
  unsigned short* hsb = w + 4718592;          // 4194304  (dead after gemm_qkv -> num0; reused: f1b)
  unsigned short* qb  = w + 8912896;          // 4194304  (reused: yb, f2b)
  unsigned short* kb  = w + 13107200;         // 1048576
  unsigned short* vt  = w + 14155776;         // 1048576
  unsigned short* att = w + 15204352;         // 4194304  (num1 -> reduced in place; reused: obb)
  unsigned short* f1b = hsb;
  unsigned short* yb  = qb;
  unsigned short* obb = att;
  unsigned short* f2b = qb;
  float* lsbuf = (float*)wqb;                 // 2 x 65536 f32 = 512 KB

  dim3 blk(256);
  cvt_all<<<dim3(8704), blk, 0, stream>>>(hs, wq, wk, wv, wo, w1, w2,
                                          hsb, wqb, wkb, wvb, wob, w1b, w2b);

  gemm_qkv<<<dim3(768), blk, 0, stream>>>(hsb, wqb, wkb, wvb, bq, bk, bvp,
                                          qb, kb, vt);
  attn_mfma<<<dim3(512), dim3(512), 0, stream>>>(qb, kb, vt, hsb, att, lsbuf);
  attn_reduce<<<dim3(4096), blk, 0, stream>>>(hsb, att, lsbuf);
  gemm_wn<false><<<dim3(512), blk, 0, stream>>>(att, wob, bo, yb, 4096, 1024, 1024);
  resid_ln1<<<dim3(4096), blk, 0, stream>>>(hs, yb, lng, lnb, obb);
  gemm_wn<true><<<dim3(512), blk, 0, stream>>>(obb, w1b, b1, f1b, 4096, 1024, 1024);
  gemm_wn<false><<<dim3(512), blk, 0, stream>>>(f1b, w2b, b2, f2b, 4096, 1024, 1024);
  resid_ln2<<<dim3(4096), blk, 0, stream>>>(obb, f2b, flg, flb, out);
}

// Round 8
// 226.180 us; speedup vs baseline: 1.0433x; 1.0387x over previous
//
#include <hip/hip_runtime.h>
#include <math.h>

#define HIDDEN 1024
#define SEQ 2048

typedef __attribute__((ext_vector_type(8))) short short8;
typedef __attribute__((ext_vector_type(4))) float f32x4;

__device__ __forceinline__ unsigned short f2bf(float x) {
  union { float f; unsigned u; } c; c.f = x;
  unsigned r = c.u + 0x7FFFu + ((c.u >> 16) & 1u);
  return (unsigned short)(r >> 16);
}
__device__ __forceinline__ float bf2f(unsigned short h) {
  union { unsigned u; float f; } c; c.u = ((unsigned)h) << 16;
  return c.f;
}

// raw v_exp_f32 (exp2) without libm edge-case wrapper
__device__ __forceinline__ float fexp2(float x) {
  float r; asm("v_exp_f32 %0, %1" : "=v"(r) : "v"(x)); return r;
}

// pack two f32 -> one reg of 2 bf16 (RNE), lo in low half
__device__ __forceinline__ unsigned cvt_pk_bf16(float lo, float hi) {
  unsigned r;
  asm("v_cvt_pk_bf16_f32 %0, %1, %2" : "=v"(r) : "v"(lo), "v"(hi));
  return r;
}

// async 16B global -> LDS (wave-uniform LDS base; HW scatters lane i to base+16i)
__device__ __forceinline__ void async_copy16(const void* g, void* l) {
  __builtin_amdgcn_global_load_lds(
      (const __attribute__((address_space(1))) unsigned int*)g,
      (__attribute__((address_space(3))) unsigned int*)l, 16, 0, 0);
}

// ---------------------------------------------------------------------------
// All fp32->bf16 converts in ONE dispatch.
// ---------------------------------------------------------------------------
__global__ __launch_bounds__(256) void cvt_all(
    const float* __restrict__ hs, const float* __restrict__ wq,
    const float* __restrict__ wk, const float* __restrict__ wv,
    const float* __restrict__ wo, const float* __restrict__ w1,
    const float* __restrict__ w2,
    unsigned short* __restrict__ hsb, unsigned short* __restrict__ wqb,
    unsigned short* __restrict__ wkb, unsigned short* __restrict__ wvb,
    unsigned short* __restrict__ wob, unsigned short* __restrict__ w1b,
    unsigned short* __restrict__ w2b)
{
  const int i = blockIdx.x * 256 + threadIdx.x;
  const float* src; unsigned short* dst; int off;
  if (i < 1048576)      { src = hs; dst = hsb; off = i; }
  else if (i < 1310720) { src = wq; dst = wqb; off = i - 1048576; }
  else if (i < 1376256) { src = wk; dst = wkb; off = i - 1310720; }
  else if (i < 1441792) { src = wv; dst = wvb; off = i - 1376256; }
  else if (i < 1703936) { src = wo; dst = wob; off = i - 1441792; }
  else if (i < 1966080) { src = w1; dst = w1b; off = i - 1703936; }
  else                  { src = w2; dst = w2b; off = i - 1966080; }
  float4 v = ((const float4*)src)[off];
  ushort4 o;
  o.x = f2bf(v.x); o.y = f2bf(v.y); o.z = f2bf(v.z); o.w = f2bf(v.w);
  ((ushort4*)dst)[off] = o;
}

// ---------------------------------------------------------------------------
// bf16 MFMA GEMM v18 "gemm_wn BK=128": R7 falsified tile-ratio AND occupancy
// as the GEMM limiter (4 structures, all ~40us, all pipes <25% util ->
// per-k-step overhead: 16 x (stage, vmcnt(0) drain, barrier)). This halves
// the step count: stage BOTH 64-col halves before ONE barrier pair, 2 MFMA
// sub-steps per barrier -> 8 outer steps. LDS 48 KB -> 3 blocks/CU
// (12 waves; R5/R7 showed TLP saturates ~12 waves so 24->12 is cheap).
// Same frag/staging code per half. XCD-chunked swizzle.
// ---------------------------------------------------------------------------
template<bool RELU>
__global__ __launch_bounds__(256, 3) void gemm_wn(
    const unsigned short* __restrict__ A, const unsigned short* __restrict__ W,
    const float* __restrict__ bias, unsigned short* __restrict__ C,
    int M, int N, int K)
{
  __shared__ unsigned short As[2][64 * 64];
  __shared__ unsigned short Bs[2][128 * 64];

  const int flat = blockIdx.x;
  const int swz = (flat & 7) * ((int)gridDim.x >> 3) + (flat >> 3);
  const int ntx = N >> 7;
  const int m0 = (swz / ntx) * 64, n0 = (swz % ntx) * 128;

  const int tid = threadIdx.x;
  const int lane = tid & 63, wave = tid >> 6;
  const int ln = lane & 15, quad = lane >> 4;
  const int wm = (wave >> 1) * 32, wn = (wave & 1) * 64;

  f32x4 acc[2][4];
#pragma unroll
  for (int i = 0; i < 2; ++i)
#pragma unroll
    for (int j = 0; j < 4; ++j) acc[i][j] = (f32x4){0.f, 0.f, 0.f, 0.f};

  for (int k0 = 0; k0 < K; k0 += 128) {
#pragma unroll
    for (int half = 0; half < 2; ++half) {
      const int kh = k0 + half * 64;
#pragma unroll
      for (int it = 0; it < 2; ++it) {
        const int c = (wave * 2 + it) * 64 + lane;
        const int row = c >> 3, gc = (c & 7) ^ (row & 7);
        async_copy16(A + (size_t)(m0 + row) * K + kh + gc * 8,
                     &As[half][(wave * 2 + it) * 512]);
      }
#pragma unroll
      for (int it = 0; it < 4; ++it) {
        const int c = (wave * 4 + it) * 64 + lane;
        const int row = c >> 3, gc = (c & 7) ^ (row & 7);
        async_copy16(W + (size_t)(n0 + row) * K + kh + gc * 8,
                     &Bs[half][(wave * 4 + it) * 512]);
      }
    }
    __syncthreads();   // one drain per 128 k

#pragma unroll
    for (int half = 0; half < 2; ++half) {
      short8 af[2][2], bfr[4][2];
#pragma unroll
      for (int i = 0; i < 2; ++i) {
        const int row = wm + i * 16 + ln;
#pragma unroll
        for (int f = 0; f < 2; ++f) {
          const int ch = row * 8 + ((f * 4 + quad) ^ (row & 7));
          af[i][f] = *(const short8*)&As[half][ch * 8];
        }
      }
#pragma unroll
      for (int j = 0; j < 4; ++j) {
        const int row = wn + j * 16 + ln;
#pragma unroll
        for (int f = 0; f < 2; ++f) {
          const int ch = row * 8 + ((f * 4 + quad) ^ (row & 7));
          bfr[j][f] = *(const short8*)&Bs[half][ch * 8];
        }
      }
#pragma unroll
      for (int i = 0; i < 2; ++i)
#pragma unroll
        for (int j = 0; j < 4; ++j) {
          acc[i][j] = __builtin_amdgcn_mfma_f32_16x16x32_bf16(af[i][0], bfr[j][0], acc[i][j], 0, 0, 0);
          acc[i][j] = __builtin_amdgcn_mfma_f32_16x16x32_bf16(af[i][1], bfr[j][1], acc[i][j], 0, 0, 0);
        }
    }
    __syncthreads();   // all reads done before next stage overwrites
  }

#pragma unroll
  for (int j = 0; j < 4; ++j) {
    const int n = n0 + wn + j * 16 + ln;
    const float bv = bias[n];
#pragma unroll
    for (int i = 0; i < 2; ++i) {
#pragma unroll
      for (int rr = 0; rr < 4; ++rr) {
        const int m = m0 + wm + i * 16 + quad * 4 + rr;
        float v = acc[i][j][rr] + bv;
        if (RELU) v = fmaxf(v, 0.f);
        C[(size_t)m * N + n] = f2bf(v);
      }
    }
  }
}

// ---------------------------------------------------------------------------
// Fused QKV GEMM: 64x128 tile, SINGLE-buffered (24 KB) -> 6 blocks/CU.
// (unchanged; control)
// ---------------------------------------------------------------------------
__global__ __launch_bounds__(256) void gemm_qkv(
    const unsigned short* __restrict__ A,
    const unsigned short* __restrict__ Wq, const unsigned short* __restrict__ Wk,
    const unsigned short* __restrict__ Wv,
    const float* __restrict__ bq, const float* __restrict__ bk,
    const float* __restrict__ bv,
    unsigned short* __restrict__ Qo, unsigned short* __restrict__ Ko,
    unsigned short* __restrict__ Vt)
{
  __shared__ unsigned short As[64 * 64];
  __shared__ unsigned short Bs[128 * 64];

  const int flat = blockIdx.x;                 // 0..767
  const int swz = (flat & 7) * 96 + (flat >> 3);
  const int bx = swz % 12, by = swz / 12;

  int mode, nw0;
  const unsigned short* W;
  const float* bias;
  if (bx < 8)       { mode = 0; W = Wq; bias = bq; nw0 = bx * 128; }
  else if (bx < 10) { mode = 1; W = Wk; bias = bk; nw0 = (bx - 8) * 128; }
  else              { mode = 2; W = Wv; bias = bv; nw0 = (bx - 10) * 128; }

  const int tid = threadIdx.x;
  const int lane = tid & 63, wave = tid >> 6;
  const int ln = lane & 15, quad = lane >> 4;
  const int wm = (wave >> 1) * 32, wn = (wave & 1) * 64;
  const int m0 = by * 64;
  const int K = 1024;

  f32x4 acc[2][4];
#pragma unroll
  for (int i = 0; i < 2; ++i)
#pragma unroll
    for (int j = 0; j < 4; ++j) acc[i][j] = (f32x4){0.f, 0.f, 0.f, 0.f};

  for (int k0 = 0; k0 < K; k0 += 64) {
#pragma unroll
    for (int it = 0; it < 2; ++it) {
      const int c = (wave * 2 + it) * 64 + lane;
      const int row = c >> 3, gc = (c & 7) ^ (row & 7);
      async_copy16(A + (size_t)(m0 + row) * K + k0 + gc * 8,
                   &As[(wave * 2 + it) * 512]);
    }
#pragma unroll
    for (int it = 0; it < 4; ++it) {
      const int c = (wave * 4 + it) * 64 + lane;
      const int row = c >> 3, gc = (c & 7) ^ (row & 7);
      async_copy16(W + (size_t)(nw0 + row) * K + k0 + gc * 8,
                   &Bs[(wave * 4 + it) * 512]);
    }
    __syncthreads();

    short8 af[2][2], bfr[4][2];
#pragma unroll
    for (int i = 0; i < 2; ++i) {
      const int row = wm + i * 16 + ln;
#pragma unroll
      for (int f = 0; f < 2; ++f) {
        const int ch = row * 8 + ((f * 4 + quad) ^ (row & 7));
        af[i][f] = *(const short8*)&As[ch * 8];
      }
    }
#pragma unroll
    for (int j = 0; j < 4; ++j) {
      const int row = wn + j * 16 + ln;
#pragma unroll
      for (int f = 0; f < 2; ++f) {
        const int ch = row * 8 + ((f * 4 + quad) ^ (row & 7));
        bfr[j][f] = *(const short8*)&Bs[ch * 8];
      }
    }
#pragma unroll
    for (int i = 0; i < 2; ++i)
#pragma unroll
      for (int j = 0; j < 4; ++j) {
        acc[i][j] = __builtin_amdgcn_mfma_f32_16x16x32_bf16(af[i][0], bfr[j][0], acc[i][j], 0, 0, 0);
        acc[i][j] = __builtin_amdgcn_mfma_f32_16x16x32_bf16(af[i][1], bfr[j][1], acc[i][j], 0, 0, 0);
      }
    __syncthreads();
  }

#pragma unroll
  for (int j = 0; j < 4; ++j) {
    const int nl = nw0 + wn + j * 16 + ln;
    const float bvv = bias[nl];
#pragma unroll
    for (int i = 0; i < 2; ++i) {
#pragma unroll
      for (int rr = 0; rr < 4; ++rr) {
        const int m = m0 + wm + i * 16 + quad * 4 + rr;
        const float v = acc[i][j][rr] + bvv;
        if (mode == 0) {
          Qo[(size_t)m * 1024 + nl] = f2bf(v);
        } else if (mode == 1) {
          Ko[(size_t)m * 256 + nl] = f2bf(v);
        } else {
          const int b = m >> 11, s = m & 2047;
          Vt[((size_t)b * 256 + nl) * SEQ + s] = f2bf(v);
        }
      }
    }
  }
}

// ---------------------------------------------------------------------------
// MFMA flash attention v15 (REVERT from v16): split-KV, 4 waves x qg=4,
// 256 thr, __launch_bounds__(256,2) -> 2 blocks/CU, 8 waves/CU. Measured
// 41.5us in R5 vs v16's 44 (qg=4 traffic advantage > extra TLP; attn TLP
// saturates ~8 waves/CU). Softmax in two qg-halves to cap live VGPRs.
// sigma key-perm in-register P (conflicts=0), dbuf K/V 32 KB, vmcnt(4),
// XCD chunk = one (b,g).
// ---------------------------------------------------------------------------
__global__ __launch_bounds__(256, 2) void attn_mfma(
    const unsigned short* __restrict__ Q, const unsigned short* __restrict__ Kb,
    const unsigned short* __restrict__ Vt,
    unsigned short* __restrict__ N0, unsigned short* __restrict__ N1,
    float* __restrict__ LS)
{
  __shared__ unsigned short Ks[2][64 * 64];
  __shared__ unsigned short Vs[2][64 * 64];

  // XCD-chunked bijective swizzle over 512 blocks (chunk of 64 = one (b,g))
  const int hwb = blockIdx.x;
  const int swz = (hwb & 7) * 64 + (hwb >> 3);
  const int qblk = swz & 7, half = (swz >> 3) & 1, h = (swz >> 4) & 15, b = swz >> 8;
  const int g = h >> 2;

  unsigned short* __restrict__ numO = half ? N1 : N0;
  float* __restrict__ lsO = LS + half * 65536;

  const int tid = threadIdx.x, lane = tid & 63, wave = tid >> 6;
  const int ln = lane & 15, quad = lane >> 4, q8 = quad * 8;
  const int s0 = qblk * 256;
  const float qscale = 0.125f * 1.44269504f;  // softmax scale * log2(e)

  // swizzle constants
  const int ln7 = ln & 7;
  const int x0 = (quad ^ ln7) * 8;        // K/V chunk offset for cols q8
  const int x1 = ((4 + quad) ^ ln7) * 8;  // for cols 32+q8

  // all-ones bf16 B-frag for MFMA row-sums
  short8 ones;
#pragma unroll
  for (int e = 0; e < 8; ++e) ones[e] = (short)0x3F80;

  // ---- Q B-frags straight from global, pre-scaled (4 q-groups per wave)
  short8 qf[4][2];
#pragma unroll
  for (int qg = 0; qg < 4; ++qg) {
    const unsigned short* qsrc =
        Q + ((size_t)(b * SEQ + s0 + wave * 64 + qg * 16 + ln)) * 1024 + h * 64 + q8;
    qf[qg][0] = *(const short8*)qsrc;
    qf[qg][1] = *(const short8*)(qsrc + 32);
#pragma unroll
    for (int e = 0; e < 8; ++e) {
      qf[qg][0][e] = (short)f2bf(bf2f((unsigned short)qf[qg][0][e]) * qscale);
      qf[qg][1][e] = (short)f2bf(bf2f((unsigned short)qf[qg][1][e]) * qscale);
    }
  }

  // staging: chunk c = (wave*2+it)*64 + lane; LDS row=c>>3; gcc=(c&7)^(row&7)
  const int srow = lane >> 3;
  const int sgcc = (lane & 7) ^ srow;

  auto stage = [&](int t0, int p) {
#pragma unroll
    for (int it = 0; it < 2; ++it) {
      const int row = wave * 16 + it * 8 + srow;
      // sigma: key bit perm {r5,r3,r2,r4,r1,r0} -> QK out slots == PV A-frag
      const int skey = (row & 32) | ((row & 8) << 1) | ((row & 4) << 1) |
                       ((row & 16) >> 2) | (row & 3);
      async_copy16(Kb + (size_t)(b * SEQ + t0 + skey) * 256 + g * 64 + sgcc * 8,
                   &Ks[p][(wave * 2 + it) * 512]);
      async_copy16(Vt + (size_t)(b * 256 + g * 64 + row) * SEQ + t0 + sgcc * 8,
                   &Vs[p][(wave * 2 + it) * 512]);
    }
  };

  f32x4 of[4][4];
  f32x4 ls[4];
#pragma unroll
  for (int qg = 0; qg < 4; ++qg) {
    ls[qg] = (f32x4){0.f, 0.f, 0.f, 0.f};
#pragma unroll
    for (int jd = 0; jd < 4; ++jd) of[qg][jd] = (f32x4){0.f, 0.f, 0.f, 0.f};
  }

  const int tbase = half * 16;          // this half's first KV tile
  stage(tbase * 64, 0);                 // prologue prefetch (4 DMAs/wave)

  for (int tt = 0; tt < 16; ++tt) {
    const int p = tt & 1;
    if (tt < 15) {
      stage((tbase + tt + 1) * 64, p ^ 1);             // 4 new DMAs in flight
      asm volatile("s_waitcnt vmcnt(4)" ::: "memory"); // wait only tile-t DMAs
    } else {
      asm volatile("s_waitcnt vmcnt(0)" ::: "memory");
    }
    __builtin_amdgcn_s_barrier();                      // tile t fully in LDS
    asm volatile("" ::: "memory");

    // ---- QK^T + softmax in two qg-halves (live sc halved: 32 f32 not 64)
    short8 pf[4][2];
#pragma unroll
    for (int hf = 0; hf < 2; ++hf) {
      f32x4 sc[2][4];
#pragma unroll
      for (int jn = 0; jn < 4; ++jn) {
        const int krow = (jn * 16 + ln) * 64;
        const short8 kf0 = *(const short8*)&Ks[p][krow + x0];
        const short8 kf1 = *(const short8*)&Ks[p][krow + x1];
#pragma unroll
        for (int q2 = 0; q2 < 2; ++q2) {
          const int qg = hf * 2 + q2;
          f32x4 z = (f32x4){0.f, 0.f, 0.f, 0.f};
          z = __builtin_amdgcn_mfma_f32_16x16x32_bf16(kf0, qf[qg][0], z, 0, 0, 0);
          z = __builtin_amdgcn_mfma_f32_16x16x32_bf16(kf1, qf[qg][1], z, 0, 0, 0);
          sc[q2][jn] = z;
        }
      }
#pragma unroll
      for (int q2 = 0; q2 < 2; ++q2) {
        const int qg = hf * 2 + q2;
#pragma unroll
        for (int jn = 0; jn < 4; ++jn)
#pragma unroll
          for (int r = 0; r < 4; ++r) sc[q2][jn][r] = fexp2(sc[q2][jn][r]);
#pragma unroll
        for (int F = 0; F < 2; ++F) {
          union { unsigned u[4]; short8 s; } pk;
          pk.u[0] = cvt_pk_bf16(sc[q2][2 * F][0], sc[q2][2 * F][1]);
          pk.u[1] = cvt_pk_bf16(sc[q2][2 * F][2], sc[q2][2 * F][3]);
          pk.u[2] = cvt_pk_bf16(sc[q2][2 * F + 1][0], sc[q2][2 * F + 1][1]);
          pk.u[3] = cvt_pk_bf16(sc[q2][2 * F + 1][2], sc[q2][2 * F + 1][3]);
          pf[qg][F] = pk.s;
        }
        ls[qg] = __builtin_amdgcn_mfma_f32_16x16x32_bf16(pf[qg][0], ones, ls[qg], 0, 0, 0);
        ls[qg] = __builtin_amdgcn_mfma_f32_16x16x32_bf16(pf[qg][1], ones, ls[qg], 0, 0, 0);
      }
    }

    // ---- PV: vf frags shared by all 4 q-groups (natural key order)
#pragma unroll
    for (int jd = 0; jd < 4; ++jd) {
      const int vrow = (jd * 16 + ln) * 64;
      const short8 vf0 = *(const short8*)&Vs[p][vrow + x0];
      const short8 vf1 = *(const short8*)&Vs[p][vrow + x1];
#pragma unroll
      for (int qg = 0; qg < 4; ++qg) {
        of[qg][jd] = __builtin_amdgcn_mfma_f32_16x16x32_bf16(pf[qg][0], vf0, of[qg][jd], 0, 0, 0);
        of[qg][jd] = __builtin_amdgcn_mfma_f32_16x16x32_bf16(pf[qg][1], vf1, of[qg][jd], 0, 0, 0);
      }
    }

    asm volatile("" ::: "memory");
    __builtin_amdgcn_s_barrier();   // all buf-p reads done before t+1 overwrites
    asm volatile("" ::: "memory");
  }

  // ---- UNNORMALIZED packed numerator store + row-sum store
#pragma unroll
  for (int qg = 0; qg < 4; ++qg) {
    const int sbase = s0 + wave * 64 + qg * 16 + quad * 4;
    if (ln == 0) {  // lanes 0,16,32,48: ls for rows quad*4+r
#pragma unroll
      for (int r = 0; r < 4; ++r)
        lsO[(b * 16 + h) * 2048 + sbase + r] = ls[qg][r];
    }
#pragma unroll
    for (int jd = 0; jd < 4; ++jd) {
      const int d = jd * 16 + ln;
      ushort4 ov;
      ov.x = f2bf(of[qg][jd][0]);
      ov.y = f2bf(of[qg][jd][1]);
      ov.z = f2bf(of[qg][jd][2]);
      ov.w = f2bf(of[qg][jd][3]);
      *(ushort4*)&numO[((size_t)b * 1024 + h * 64 + d) * SEQ + sbase] = ov;
    }
  }
}

// ---------------------------------------------------------------------------
// Split-KV reduce: att = (num0 + att{=num1}) / (ls0 + ls1). In-place safe.
// ---------------------------------------------------------------------------
__global__ __launch_bounds__(256) void attn_reduce(
    const unsigned short* __restrict__ N0, unsigned short* att,
    const float* __restrict__ LS)
{
  const int i = (blockIdx.x * 256 + threadIdx.x) * 4;  // flat into [b][1024][2048]
  const int row = i >> 11, s = i & 2047;
  const int h = (row >> 6) & 15, b = row >> 10;
  const int lsi = (b * 16 + h) * 2048 + s;
  const float4 l0 = *(const float4*)&LS[lsi];
  const float4 l1 = *(const float4*)&LS[65536 + lsi];
  const ushort4 a = *(const ushort4*)&N0[i];
  const ushort4 c = *(const ushort4*)&att[i];
  ushort4 o;
  o.x = f2bf((bf2f(a.x) + bf2f(c.x)) / (l0.x + l1.x));
  o.y = f2bf((bf2f(a.y) + bf2f(c.y)) / (l0.y + l1.y));
  o.z = f2bf((bf2f(a.z) + bf2f(c.z)) / (l0.z + l1.z));
  o.w = f2bf((bf2f(a.w) + bf2f(c.w)) / (l0.w + l1.w));
  *(ushort4*)&att[i] = o;
}

// ---------------------------------------------------------------------------
// Residual + LayerNorm. One block per row (1024 cols), 256 thr x 4.
// ---------------------------------------------------------------------------
__device__ __forceinline__ void ln_core(float x[4], const float* gam, const float* bet,
                                        int tid, float out[4]) {
  float s1 = x[0] + x[1] + x[2] + x[3];
  float s2 = x[0] * x[0] + x[1] * x[1] + x[2] * x[2] + x[3] * x[3];
#pragma unroll
  for (int off = 1; off < 64; off <<= 1) {
    s1 += __shfl_xor(s1, off);
    s2 += __shfl_xor(s2, off);
  }
  __shared__ float r1[4], r2[4];
  const int wave = tid >> 6;
  if ((tid & 63) == 0) { r1[wave] = s1; r2[wave] = s2; }
  __syncthreads();
  s1 = r1[0] + r1[1] + r1[2] + r1[3];
  s2 = r2[0] + r2[1] + r2[2] + r2[3];
  const float mu  = s1 * (1.0f / HIDDEN);
  const float var = s2 * (1.0f / HIDDEN) - mu * mu;
  const float inv = rsqrtf(var + 1e-5f);
  float4 gv = *(const float4*)&gam[tid * 4];
  float4 bv = *(const float4*)&bet[tid * 4];
  out[0] = (x[0] - mu) * inv * gv.x + bv.x;
  out[1] = (x[1] - mu) * inv * gv.y + bv.y;
  out[2] = (x[2] - mu) * inv * gv.z + bv.z;
  out[3] = (x[3] - mu) * inv * gv.w + bv.w;
}

__global__ __launch_bounds__(256) void resid_ln1(
    const float* __restrict__ X, const unsigned short* __restrict__ Y,
    const float* __restrict__ gam, const float* __restrict__ bet,
    unsigned short* __restrict__ outb)
{
  const int row = blockIdx.x, tid = threadIdx.x;
  const size_t base = (size_t)row * HIDDEN + tid * 4;
  float4 a = *(const float4*)&X[base];
  ushort4 yv = *(const ushort4*)&Y[base];
  float x[4] = {a.x + bf2f(yv.x), a.y + bf2f(yv.y), a.z + bf2f(yv.z), a.w + bf2f(yv.w)};
  float o[4];
  ln_core(x, gam, bet, tid, o);
  ushort4 ov;
  ov.x = f2bf(o[0]); ov.y = f2bf(o[1]); ov.z = f2bf(o[2]); ov.w = f2bf(o[3]);
  *(ushort4*)&outb[base] = ov;
}

__global__ __launch_bounds__(256) void resid_ln2(
    const unsigned short* __restrict__ X, const unsigned short* __restrict__ Y,
    const float* __restrict__ gam, const float* __restrict__ bet,
    float* __restrict__ out)
{
  const int row = blockIdx.x, tid = threadIdx.x;
  const size_t base = (size_t)row * HIDDEN + tid * 4;
  ushort4 xv = *(const ushort4*)&X[base];
  ushort4 yv = *(const ushort4*)&Y[base];
  float x[4] = {bf2f(xv.x) + bf2f(yv.x), bf2f(xv.y) + bf2f(yv.y),
                bf2f(xv.z) + bf2f(yv.z), bf2f(xv.w) + bf2f(yv.w)};
  float o[4];
  ln_core(x, gam, bet, tid, o);
  float4 ov; ov.x = o[0]; ov.y = o[1]; ov.z = o[2]; ov.w = o[3];
  *(float4*)&out[base] = ov;
}

// ---------------------------------------------------------------------------
extern "C" void kernel_launch(void* const* d_in, const int* in_sizes, int n_in,
                              void* d_out, int out_size, void* d_ws, size_t ws_size,
                              hipStream_t stream)
{
  (void)in_sizes; (void)n_in; (void)out_size; (void)ws_size;
  const float* hs  = (const float*)d_in[0];
  const float* wq  = (const float*)d_in[1];
  const float* bq  = (const float*)d_in[2];
  const float* wk  = (const float*)d_in[3];
  const float* bk  = (const float*)d_in[4];
  const float* wv  = (const float*)d_in[5];
  const float* bvp = (const float*)d_in[6];
  const float* wo  = (const float*)d_in[7];
  const float* bo  = (const float*)d_in[8];
  const float* lng = (const float*)d_in[9];
  const float* lnb = (const float*)d_in[10];
  const float* w1  = (const float*)d_in[11];
  const float* b1  = (const float*)d_in[12];
  const float* w2  = (const float*)d_in[13];
  const float* b2  = (const float*)d_in[14];
  const float* flg = (const float*)d_in[15];
  const float* flb = (const float*)d_in[16];
  float* out = (float*)d_out;

  unsigned short* w = (unsigned short*)d_ws;
  unsigned short* wqb = w;                    // 1048576  (dead after gemm_qkv -> ls buf)
  unsigned short* wkb = w + 1048576;          //  262144
  unsigned short* wvb = w + 1310720;          //  262144
  unsigned short* wob = w + 1572864;          // 1048576
  unsigned short* w1b = w + 2621440;          // 1048576
  unsigned short* w2b = w + 3670016;          // 1048576
  unsigned short* hsb = w + 4718592;          // 4194304  (dead after gemm_qkv -> num0; reused: f1b)
  unsigned short* qb  = w + 8912896;          // 4194304  (reused: yb, f2b)
  unsigned short* kb  = w + 13107200;         // 1048576
  unsigned short* vt  = w + 14155776;         // 1048576
  unsigned short* att = w + 15204352;         // 4194304  (num1 -> reduced in place; reused: obb)
  unsigned short* f1b = hsb;
  unsigned short* yb  = qb;
  unsigned short* obb = att;
  unsigned short* f2b = qb;
  float* lsbuf = (float*)wqb;                 // 2 x 65536 f32 = 512 KB

  dim3 blk(256);
  cvt_all<<<dim3(8704), blk, 0, stream>>>(hs, wq, wk, wv, wo, w1, w2,
                                          hsb, wqb, wkb, wvb, wob, w1b, w2b);

  gemm_qkv<<<dim3(768), blk, 0, stream>>>(hsb, wqb, wkb, wvb, bq, bk, bvp,
                                          qb, kb, vt);
  attn_mfma<<<dim3(512), blk, 0, stream>>>(qb, kb, vt, hsb, att, lsbuf);
  attn_reduce<<<dim3(4096), blk, 0, stream>>>(hsb, att, lsbuf);
  gemm_wn<false><<<dim3(512), blk, 0, stream>>>(att, wob, bo, yb, 4096, 1024, 1024);
  resid_ln1<<<dim3(4096), blk, 0, stream>>>(hs, yb, lng, lnb, obb);
  gemm_wn<true><<<dim3(512), blk, 0, stream>>>(obb, w1b, b1, f1b, 4096, 1024, 1024);
  gemm_wn<false><<<dim3(512), blk, 0, stream>>>(f1b, w2b, b2, f2b, 4096, 1024, 1024);
  resid_ln2<<<dim3(4096), blk, 0, stream>>>(obb, f2b, flg, flb, out);
}